// Round 5
// baseline (154.802 us; speedup 1.0000x reference)
//
#include <hip/hip_runtime.h>
#include <hip/hip_bf16.h>
#include <math.h>

#define HIDDEN 512
#define ATTEN  512
#define BATCH  32
#define STEP   2048

#define BM 128                // rows per scores block
#define BN 128                // atten cols per block (4 N-slices)
#define NS (ATTEN / BN)       // 4
#define BK 32                 // K tile
#define NT (HIDDEN / BK)      // 16 K-tiles
#define THREADS 512           // 8 waves: 2(M) x 4(N), wave tile 64x32

#define NCH 16                // s-chunks in weighted-sum kernel
#define CHS (STEP / NCH)

typedef __attribute__((ext_vector_type(8))) short bf16x8;
typedef __attribute__((ext_vector_type(4))) float f32x4;

// batch_lens may arrive as int64 (reference dtype) or int32 (jax without x64).
// Values >= 1, so int32-view index 1 == 0 iff the buffer is int64.
__device__ __forceinline__ long long load_len(const int* lens_raw, int b) {
    bool is64 = (lens_raw[1] == 0);
    if (is64) return ((const long long*)lens_raw)[b];
    return (long long)lens_raw[b];
}

__device__ __forceinline__ short f2bf(float x) {        // RNE fp32 -> bf16 bits
    unsigned u = __float_as_uint(x);
    unsigned r = (u + 0x7FFFu + ((u >> 16) & 1u)) >> 16;
    return (short)r;
}
__device__ __forceinline__ float bf2f(short s) {
    return __uint_as_float(((unsigned)(unsigned short)s) << 16);
}

__device__ __forceinline__ float fast_tanh(float x) {
    float e = __expf(2.0f * x);         // saturates correctly at +-inf
    return 1.0f - 2.0f / (e + 1.0f);
}

// K0: pre-swizzled split-bf16 W for global_load_lds staging.
// LDS B layout (per N-slice ns, K-tile kt): col c(0..127) owns a 128B row
// = 8 slots of 16B; slot16 = (p*4 + s) ^ (c&7), p=hi/lo, s=k-subslot(8 bf16).
// global_load_lds writes chunk n -> LDS byte n*16, so global chunk order is
// n = c*8 + slot16. wglds[((ns*16+kt)*1024 + n)*8 + j].
__global__ __launch_bounds__(512) void wsplit_kernel(
    const float* __restrict__ W, short* __restrict__ wglds)
{
    int a = blockIdx.x;       // 0..511  (atten col)
    int h = threadIdx.x;      // 0..511  (hidden = k)
    float v = W[(size_t)h * ATTEN + a];
    short hi = f2bf(v);
    short lo = f2bf(v - bf2f(hi));
    int ns = a >> 7, c = a & 127;
    int kt = h >> 5, s = (h >> 3) & 3, j = h & 7;
    size_t tb = ((size_t)ns * NT + kt) * 1024;
    int n_hi = c * 8 + ((s) ^ (c & 7));
    int n_lo = c * 8 + ((4 + s) ^ (c & 7));
    wglds[(tb + n_hi) * 8 + j] = hi;
    wglds[(tb + n_lo) * 8 + j] = lo;
}

// K1: partial scores over a 128-col slice; A+B double-buffered in LDS,
// issue-early staging, one barrier per K-tile.
__global__ __launch_bounds__(THREADS, 4) void scores_mfma_kernel(
    const float* __restrict__ X,        // [B*S*H] fp32
    const int*   __restrict__ lens_raw,
    const short* __restrict__ wglds,    // pre-swizzled split-bf16 W
    const float* __restrict__ bias,
    const float* __restrict__ ctx,
    float* __restrict__ scores_part)    // [NS][B*S]
{
    __shared__ char smem[64 * 1024];
    char* smA0 = smem;                  // 16 KB each
    char* smA1 = smem + 16 * 1024;
    char* smB0 = smem + 32 * 1024;
    char* smB1 = smem + 48 * 1024;

    const int tiles_per_b = STEP / BM;  // 16
    int mt = blockIdx.x;
    int ns = blockIdx.y;                // N-slice 0..3
    int b  = mt / tiles_per_b;
    int s0 = (mt % tiles_per_b) * BM;
    long long len = load_len(lens_raw, b);
    if ((long long)s0 >= len) return;

    int t = threadIdx.x;
    int wave = t >> 6, lane = t & 63;
    int wrow = wave >> 2, wcol = wave & 3;
    int l15 = lane & 15, l4 = lane >> 4;

    // A staging coords: thread -> (row ar, k-subslot aq)
    int ar = t >> 2, aq = t & 3;
    const float* xrow = X + ((size_t)b * STEP + s0 + ar) * HIDDEN + aq * 8;

    const short* wbase = wglds + (size_t)ns * NT * 1024 * 8;
    int wvuni16 = (t & ~63) * 16;       // wave-uniform LDS byte base

    float4 px0, px1;                    // X prefetch registers

    f32x4 acc[4][2];
#pragma unroll
    for (int mi = 0; mi < 4; ++mi)
#pragma unroll
        for (int ni = 0; ni < 2; ++ni)
            acc[mi][ni] = (f32x4){0.f, 0.f, 0.f, 0.f};

// issue next tile's loads: B -> LDS (DMA), X -> regs. No waits here.
#define ISSUE(KT, SB)                                                        \
    do {                                                                     \
        _Pragma("unroll")                                                    \
        for (int i = 0; i < 2; ++i) {                                        \
            const short* g = wbase + ((size_t)(KT) * 1024 + i * 512 + t) * 8;\
            char* l = (SB) + i * 512 * 16 + wvuni16;                         \
            __builtin_amdgcn_global_load_lds(                                \
                (const __attribute__((address_space(1))) unsigned int*)g,    \
                (__attribute__((address_space(3))) unsigned int*)l,          \
                16, 0, 0);                                                   \
        }                                                                    \
        px0 = *(const float4*)(xrow + (KT) * BK);                            \
        px1 = *(const float4*)(xrow + (KT) * BK + 4);                        \
    } while (0)

// convert prefetched X -> hi/lo bf16, swizzled ds_write (waits px vmcnt)
#define AWRITE(SA)                                                           \
    do {                                                                     \
        float xs[8] = {px0.x, px0.y, px0.z, px0.w, px1.x, px1.y, px1.z, px1.w};\
        bf16x8 hv, lv;                                                       \
        _Pragma("unroll")                                                    \
        for (int j = 0; j < 8; ++j) {                                        \
            short h_ = f2bf(xs[j]);                                          \
            hv[j] = h_;                                                      \
            lv[j] = f2bf(xs[j] - bf2f(h_));                                  \
        }                                                                    \
        int rx = ar & 7;                                                     \
        *(bf16x8*)((SA) + ar * 128 + (((aq) ^ rx) << 4)) = hv;               \
        *(bf16x8*)((SA) + ar * 128 + (((4 + aq) ^ rx) << 4)) = lv;           \
    } while (0)

#define COMPUTE(SA, SB)                                                      \
    do {                                                                     \
        bf16x8 ah[4], al[4];                                                 \
        _Pragma("unroll")                                                    \
        for (int mi = 0; mi < 4; ++mi) {                                     \
            int row = wrow * 64 + mi * 16 + l15;                             \
            int rx = row & 7;                                                \
            ah[mi] = *(const bf16x8*)((SA) + row * 128 + ((l4 ^ rx) << 4));  \
            al[mi] = *(const bf16x8*)((SA) + row * 128 + (((4 + l4) ^ rx) << 4)); \
        }                                                                    \
        _Pragma("unroll")                                                    \
        for (int ni = 0; ni < 2; ++ni) {                                     \
            int col = wcol * 32 + ni * 16 + l15;                             \
            int cx = col & 7;                                                \
            bf16x8 bh = *(const bf16x8*)((SB) + col * 128 + ((l4 ^ cx) << 4)); \
            bf16x8 bl = *(const bf16x8*)((SB) + col * 128 + (((4 + l4) ^ cx) << 4)); \
            _Pragma("unroll")                                                \
            for (int mi = 0; mi < 4; ++mi) {                                 \
                acc[mi][ni] = __builtin_amdgcn_mfma_f32_16x16x32_bf16(       \
                    ah[mi], bh, acc[mi][ni], 0, 0, 0);                       \
                acc[mi][ni] = __builtin_amdgcn_mfma_f32_16x16x32_bf16(       \
                    ah[mi], bl, acc[mi][ni], 0, 0, 0);                       \
                acc[mi][ni] = __builtin_amdgcn_mfma_f32_16x16x32_bf16(       \
                    al[mi], bh, acc[mi][ni], 0, 0, 0);                       \
            }                                                                \
        }                                                                    \
    } while (0)

    ISSUE(0, smB0);
    AWRITE(smA0);
    __syncthreads();

    for (int kt = 0; kt < NT; kt += 2) {
        // buf0 compute; stage kt+1 into buf1 (buf1 free since last barrier)
        ISSUE(kt + 1, smB1);
        COMPUTE(smA0, smB0);
        AWRITE(smA1);
        __syncthreads();                 // drains B-DMA(kt+1); A1 visible
        // buf1 compute; stage kt+2 into buf0 (all waves done with buf0)
        if (kt + 2 < NT) {
            ISSUE(kt + 2, smB0);
            COMPUTE(smA1, smB1);
            AWRITE(smA0);
        } else {
            COMPUTE(smA1, smB1);
        }
        __syncthreads();
    }
#undef ISSUE
#undef AWRITE
#undef COMPUTE

    // fused epilogue: tanh(acc+bias)*ctx reduced over this slice's 128 cols
    float bi[2], ci[2];
#pragma unroll
    for (int ni = 0; ni < 2; ++ni) {
        int a = ns * BN + wcol * 32 + ni * 16 + l15;
        bi[ni] = bias[a];
        ci[ni] = ctx[a];
    }
    float* partial = (float*)smA0;       // [4 wcol][BM]
#pragma unroll
    for (int mi = 0; mi < 4; ++mi) {
#pragma unroll
        for (int reg = 0; reg < 4; ++reg) {
            float s = 0.f;
#pragma unroll
            for (int ni = 0; ni < 2; ++ni)
                s += fast_tanh(acc[mi][ni][reg] + bi[ni]) * ci[ni];
            s += __shfl_xor(s, 1);
            s += __shfl_xor(s, 2);
            s += __shfl_xor(s, 4);
            s += __shfl_xor(s, 8);
            if (l15 == 0) {
                int row = wrow * 64 + mi * 16 + l4 * 4 + reg;  // C/D layout
                partial[wcol * BM + row] = s;
            }
        }
    }
    __syncthreads();
    if (t < BM) {
        float v = partial[0 * BM + t] + partial[1 * BM + t]
                + partial[2 * BM + t] + partial[3 * BM + t];
        scores_part[((size_t)ns * BATCH + b) * STEP + s0 + t] = v;
    }
}

// K2: masked softmax; sums the 4 N-slice partials; atten aliases slice-0
// buffer (each thread reads its s-values before writing them).
__global__ __launch_bounds__(256) void softmax_kernel(
    const float* __restrict__ sp, const int* __restrict__ lens_raw,
    float* __restrict__ atten)
{
    __shared__ float wmax[4], wsum[4];
    int b = blockIdx.x;
    long long len = load_len(lens_raw, b);
    int t = threadIdx.x;
    const float* r0 = sp + (size_t)b * STEP;
    const float* r1 = r0 + (size_t)BATCH * STEP;
    const float* r2 = r1 + (size_t)BATCH * STEP;
    const float* r3 = r2 + (size_t)BATCH * STEP;
    float* arow = atten + (size_t)b * STEP;

    float sv[STEP / 256];
    float locmax = -INFINITY;
#pragma unroll
    for (int k = 0; k < 8; ++k) {
        int s = t + k * 256;
        float v = ((long long)s < len) ? (r0[s] + r1[s] + r2[s] + r3[s])
                                       : -INFINITY;
        sv[k] = v;
        locmax = fmaxf(locmax, v);
    }
    for (int o = 1; o < 64; o <<= 1) locmax = fmaxf(locmax, __shfl_xor(locmax, o));
    int wave = t >> 6, lane = t & 63;
    if (lane == 0) wmax[wave] = locmax;
    __syncthreads();
    float gmax = fmaxf(fmaxf(wmax[0], wmax[1]), fmaxf(wmax[2], wmax[3]));

    float ev[8];
    float locsum = 0.f;
#pragma unroll
    for (int k = 0; k < 8; ++k) {
        float e = (sv[k] == -INFINITY) ? 0.f : expf(sv[k] - gmax);
        ev[k] = e;
        locsum += e;
    }
    for (int o = 1; o < 64; o <<= 1) locsum += __shfl_xor(locsum, o);
    if (lane == 0) wsum[wave] = locsum;
    __syncthreads();
    float inv = 1.f / (wsum[0] + wsum[1] + wsum[2] + wsum[3]);
#pragma unroll
    for (int k = 0; k < 8; ++k) {
        int s = t + k * 256;
        arow[s] = ev[k] * inv;
    }
}

// K3a: partial[b,ch,h] = sum_{s in chunk, s<len} atten[b,s] * X[b,s,h]
__global__ __launch_bounds__(256) void wsum_kernel(
    const float* __restrict__ X, const int* __restrict__ lens_raw,
    const float* __restrict__ atten, float* __restrict__ partial)
{
    int ch = blockIdx.x;
    int b  = blockIdx.y;
    long long len = load_len(lens_raw, b);
    int t = threadIdx.x;
    int s0 = ch * CHS;
    long long send_ll = (long long)(s0 + CHS);
    if (send_ll > len) send_ll = len;
    int send = (int)send_ll;

    const float* arow = atten + (size_t)b * STEP;
    float acc0 = 0.f, acc1 = 0.f;
    for (int s = s0; s < send; ++s) {
        float a = arow[s];
        const float* xr = X + ((size_t)b * STEP + s) * HIDDEN;
        acc0 = fmaf(a, xr[t], acc0);
        acc1 = fmaf(a, xr[t + 256], acc1);
    }
    float* prow = partial + ((size_t)b * NCH + ch) * HIDDEN;
    prow[t] = acc0;            // skipped chunks write zeros
    prow[t + 256] = acc1;
}

// K3b: out[b,h] = sum_ch partial[b,ch,h]
__global__ __launch_bounds__(256) void finalize_kernel(
    const float* __restrict__ partial, float* __restrict__ out)
{
    int b = blockIdx.x;
    int t = threadIdx.x;
    float a0 = 0.f, a1 = 0.f;
#pragma unroll
    for (int ch = 0; ch < NCH; ++ch) {
        const float* prow = partial + ((size_t)b * NCH + ch) * HIDDEN;
        a0 += prow[t];
        a1 += prow[t + 256];
    }
    out[(size_t)b * HIDDEN + t] = a0;
    out[(size_t)b * HIDDEN + t + 256] = a1;
}

extern "C" void kernel_launch(void* const* d_in, const int* in_sizes, int n_in,
                              void* d_out, int out_size, void* d_ws, size_t ws_size,
                              hipStream_t stream) {
    const float* X    = (const float*)d_in[0];
    const int*   lens = (const int*)d_in[1];   // dtype sniffed on device
    const float* W    = (const float*)d_in[2];
    const float* bias = (const float*)d_in[3];
    const float* ctx  = (const float*)d_in[4];
    float* out = (float*)d_out;

    char* ws = (char*)d_ws;
    float* sp      = (float*)ws;                    // [4][B*S] = 1 MB
    float* atten   = sp;                            // aliases slice-0 (safe)
    float* partial = (float*)(ws + 1024 * 1024);    // 1 MB
    short* wglds   = (short*)(ws + 2048 * 1024);    // 1 MB pre-swizzled W

    wsplit_kernel<<<dim3(ATTEN), 512, 0, stream>>>(W, wglds);
    scores_mfma_kernel<<<dim3(BATCH * (STEP / BM), NS), THREADS, 0, stream>>>(
        X, lens, wglds, bias, ctx, sp);
    softmax_kernel<<<dim3(BATCH), 256, 0, stream>>>(sp, lens, atten);
    wsum_kernel<<<dim3(NCH, BATCH), 256, 0, stream>>>(X, lens, atten, partial);
    finalize_kernel<<<dim3(BATCH), 256, 0, stream>>>(partial, out);
}

// Round 6
// 144.409 us; speedup vs baseline: 1.0720x; 1.0720x over previous
//
#include <hip/hip_runtime.h>
#include <hip/hip_bf16.h>
#include <math.h>

#define HIDDEN 512
#define ATTEN  512
#define BATCH  32
#define STEP   2048

#define BM 128                // rows per scores block
#define BN 256                // atten cols per block (2 N-slices)
#define NS (ATTEN / BN)       // 2
#define BK 32                 // K tile
#define NT (HIDDEN / BK)      // 16 K-tiles
#define THREADS 512           // 8 waves: 2(M) x 4(N), wave tile 64x64

#define NCH 16                // s-chunks in weighted-sum kernel
#define CHS (STEP / NCH)

typedef __attribute__((ext_vector_type(8))) short bf16x8;
typedef __attribute__((ext_vector_type(4))) float f32x4;

// batch_lens may arrive as int64 (reference dtype) or int32 (jax without x64).
// Values >= 1, so int32-view index 1 == 0 iff the buffer is int64.
__device__ __forceinline__ long long load_len(const int* lens_raw, int b) {
    bool is64 = (lens_raw[1] == 0);
    if (is64) return ((const long long*)lens_raw)[b];
    return (long long)lens_raw[b];
}

__device__ __forceinline__ short f2bf(float x) {        // RNE fp32 -> bf16 bits
    unsigned u = __float_as_uint(x);
    unsigned r = (u + 0x7FFFu + ((u >> 16) & 1u)) >> 16;
    return (short)r;
}
__device__ __forceinline__ float bf2f(short s) {
    return __uint_as_float(((unsigned)(unsigned short)s) << 16);
}

__device__ __forceinline__ float fast_tanh(float x) {
    float e = __expf(2.0f * x);         // saturates correctly at +-inf
    return 1.0f - 2.0f / (e + 1.0f);
}

// K0: pre-swizzled split-bf16 W for global_load_lds staging (R4 layout).
// Per N-slice ns, K-tile kt: col c(0..255) owns a 128B LDS row = 8 slots of
// 16B; slot16 = (p*4 + s) ^ (c&7), p=hi/lo, s=k-subslot(8 bf16).
// global chunk order n = c*8 + slot16. wglds[((ns*16+kt)*2048 + n)*8 + j].
__global__ __launch_bounds__(512) void wsplit_kernel(
    const float* __restrict__ W, short* __restrict__ wglds)
{
    int a = blockIdx.x;       // 0..511  (atten col)
    int h = threadIdx.x;      // 0..511  (hidden = k)
    float v = W[(size_t)h * ATTEN + a];
    short hi = f2bf(v);
    short lo = f2bf(v - bf2f(hi));
    int ns = a >> 8, c = a & 255;
    int kt = h >> 5, s = (h >> 3) & 3, j = h & 7;
    size_t tb = ((size_t)ns * NT + kt) * 2048;
    int n_hi = c * 8 + ((s) ^ (c & 7));
    int n_lo = c * 8 + ((4 + s) ^ (c & 7));
    wglds[(tb + n_hi) * 8 + j] = hi;
    wglds[(tb + n_lo) * 8 + j] = lo;
}

// K1: partial scores over a 256-col slice. A 2-buf + B 3-buf in 128 KB
// dynamic LDS; loads for tile t issued at phase t-2; counted vmcnt (never 0
// in steady state) + raw s_barrier; one barrier per K-tile.
__global__ __launch_bounds__(THREADS, 2) void scores_mfma_kernel(
    const float* __restrict__ X,        // [B*S*H] fp32
    const int*   __restrict__ lens_raw,
    const short* __restrict__ wglds,    // pre-swizzled split-bf16 W
    const float* __restrict__ bias,
    const float* __restrict__ ctx,
    float* __restrict__ scores_part)    // [NS][B*S]
{
    extern __shared__ char smem[];      // 128 KB dynamic

    const int tiles_per_b = STEP / BM;  // 16
    int ns = blockIdx.x;                // N-slice 0..1 (fast-varying: L2 pairing)
    int mt = blockIdx.y;
    int b  = mt / tiles_per_b;
    int s0 = (mt % tiles_per_b) * BM;
    long long len = load_len(lens_raw, b);
    if ((long long)s0 >= len) return;

    int t = threadIdx.x;
    int wave = t >> 6, lane = t & 63;
    int wrow = wave >> 2, wcol = wave & 3;
    int l15 = lane & 15, l4 = lane >> 4;

    char* const A0 = smem;               // 16 KB each
    char* const A1 = smem + 16 * 1024;
    char* const B0 = smem + 32 * 1024;   // 32 KB each
    char* const B1 = smem + 64 * 1024;
    char* const B2 = smem + 96 * 1024;
    char* const smAarr[2] = {A0, A1};
    char* const smBarr[3] = {B0, B1, B2};

    // A staging coords: thread -> (row ar, k-subslot aq)
    int ar = t >> 2, aq = t & 3;
    const float* xrow = X + ((size_t)b * STEP + s0 + ar) * HIDDEN + aq * 8;

    const short* wbase = wglds + (size_t)ns * NT * 2048 * 8;
    int wvuni16 = (t & ~63) * 16;        // wave-uniform LDS byte base

    f32x4 acc[4][4];
#pragma unroll
    for (int mi = 0; mi < 4; ++mi)
#pragma unroll
        for (int ni = 0; ni < 4; ++ni)
            acc[mi][ni] = (f32x4){0.f, 0.f, 0.f, 0.f};

    float4 pxe0, pxe1, pxo0, pxo1;       // px sets: even-KT / odd-KT

// X loads for tile KT -> registers (2 vmem loads)
#define PXLOAD(KT, P0, P1)                                                   \
    do {                                                                     \
        P0 = *(const float4*)(xrow + (KT) * BK);                             \
        P1 = *(const float4*)(xrow + (KT) * BK + 4);                         \
    } while (0)

// B-DMA for tile KT -> LDS buffer SB (4 global_load_lds, 16B each)
#define BISSUE(KT, SB)                                                       \
    do {                                                                     \
        _Pragma("unroll")                                                    \
        for (int i = 0; i < 4; ++i) {                                        \
            const short* g = wbase + ((size_t)(KT) * 2048 + i * 512 + t) * 8;\
            char* l = (SB) + i * 8192 + wvuni16;                             \
            __builtin_amdgcn_global_load_lds(                                \
                (const __attribute__((address_space(1))) unsigned int*)g,    \
                (__attribute__((address_space(3))) unsigned int*)l,          \
                16, 0, 0);                                                   \
        }                                                                    \
    } while (0)

// convert px -> hi/lo bf16, swizzled ds_write into SA
#define AWRITE(P0, P1, SA)                                                   \
    do {                                                                     \
        float xs[8] = {P0.x, P0.y, P0.z, P0.w, P1.x, P1.y, P1.z, P1.w};      \
        bf16x8 hv, lv;                                                       \
        _Pragma("unroll")                                                    \
        for (int j = 0; j < 8; ++j) {                                        \
            short h_ = f2bf(xs[j]);                                          \
            hv[j] = h_;                                                      \
            lv[j] = f2bf(xs[j] - bf2f(h_));                                  \
        }                                                                    \
        int rx = ar & 7;                                                     \
        *(bf16x8*)((SA) + ar * 128 + (((aq) ^ rx) << 4)) = hv;               \
        *(bf16x8*)((SA) + ar * 128 + (((4 + aq) ^ rx) << 4)) = lv;           \
    } while (0)

#define COMPUTE(SA, SB)                                                      \
    do {                                                                     \
        bf16x8 ah[4], al[4];                                                 \
        _Pragma("unroll")                                                    \
        for (int mi = 0; mi < 4; ++mi) {                                     \
            int row = wrow * 64 + mi * 16 + l15;                             \
            int rx = row & 7;                                                \
            ah[mi] = *(const bf16x8*)((SA) + row * 128 + ((l4 ^ rx) << 4));  \
            al[mi] = *(const bf16x8*)((SA) + row * 128 + (((4 + l4) ^ rx) << 4)); \
        }                                                                    \
        _Pragma("unroll")                                                    \
        for (int ni = 0; ni < 4; ++ni) {                                     \
            int col = wcol * 64 + ni * 16 + l15;                             \
            int cx = col & 7;                                                \
            bf16x8 bh = *(const bf16x8*)((SB) + col * 128 + ((l4 ^ cx) << 4)); \
            bf16x8 bl = *(const bf16x8*)((SB) + col * 128 + (((4 + l4) ^ cx) << 4)); \
            _Pragma("unroll")                                                \
            for (int mi = 0; mi < 4; ++mi) {                                 \
                acc[mi][ni] = __builtin_amdgcn_mfma_f32_16x16x32_bf16(       \
                    ah[mi], bh, acc[mi][ni], 0, 0, 0);                       \
                acc[mi][ni] = __builtin_amdgcn_mfma_f32_16x16x32_bf16(       \
                    ah[mi], bl, acc[mi][ni], 0, 0, 0);                       \
                acc[mi][ni] = __builtin_amdgcn_mfma_f32_16x16x32_bf16(       \
                    al[mi], bh, acc[mi][ni], 0, 0, 0);                       \
            }                                                                \
        }                                                                    \
    } while (0)

    // prologue: tiles 0 and 1 in flight (issue order: px then B, per tile)
    PXLOAD(0, pxe0, pxe1); BISSUE(0, B0);
    PXLOAD(1, pxo0, pxo1); BISSUE(1, B1);
    asm volatile("s_waitcnt vmcnt(6)" ::: "memory");   // px(0)+B(0) done
    AWRITE(pxe0, pxe1, A0);
    asm volatile("s_waitcnt lgkmcnt(0)" ::: "memory");
    __builtin_amdgcn_s_barrier();
    __builtin_amdgcn_sched_barrier(0);

#pragma unroll
    for (int kt = 0; kt < NT; ++kt) {
        // entry: need B(kt) complete. In steady state px(kt+1)+B(kt+1)=6 may fly.
        if (kt + 1 < NT) {
            asm volatile("s_waitcnt vmcnt(6)" ::: "memory");
        } else {
            asm volatile("s_waitcnt vmcnt(0)" ::: "memory");
        }
        if (kt + 2 < NT) {
            if ((kt & 1) == 0) { PXLOAD(kt + 2, pxe0, pxe1); }
            else               { PXLOAD(kt + 2, pxo0, pxo1); }
            BISSUE(kt + 2, smBarr[(kt + 2) % 3]);
        }
        COMPUTE(smAarr[kt & 1], smBarr[kt % 3]);
        if (kt + 1 < NT) {
            if ((kt & 1) == 0) { AWRITE(pxo0, pxo1, smAarr[(kt + 1) & 1]); }
            else               { AWRITE(pxe0, pxe1, smAarr[(kt + 1) & 1]); }
            asm volatile("s_waitcnt lgkmcnt(0)" ::: "memory");
            __builtin_amdgcn_s_barrier();
            __builtin_amdgcn_sched_barrier(0);
        }
    }
#undef PXLOAD
#undef BISSUE
#undef AWRITE
#undef COMPUTE

    // fused epilogue: tanh(acc+bias)*ctx reduced over this slice's 256 cols.
    // Last COMPUTE read A1/B0; A0 free since the phase-14 barrier.
    float bi[4], ci[4];
#pragma unroll
    for (int ni = 0; ni < 4; ++ni) {
        int a = ns * BN + wcol * 64 + ni * 16 + l15;
        bi[ni] = bias[a];
        ci[ni] = ctx[a];
    }
    float* partial = (float*)A0;         // [4 wcol][BM]
#pragma unroll
    for (int mi = 0; mi < 4; ++mi) {
#pragma unroll
        for (int reg = 0; reg < 4; ++reg) {
            float s = 0.f;
#pragma unroll
            for (int ni = 0; ni < 4; ++ni)
                s += fast_tanh(acc[mi][ni][reg] + bi[ni]) * ci[ni];
            s += __shfl_xor(s, 1);
            s += __shfl_xor(s, 2);
            s += __shfl_xor(s, 4);
            s += __shfl_xor(s, 8);
            if (l15 == 0) {
                int row = wrow * 64 + mi * 16 + l4 * 4 + reg;  // C/D layout
                partial[wcol * BM + row] = s;
            }
        }
    }
    __syncthreads();
    if (t < BM) {
        float v = partial[0 * BM + t] + partial[1 * BM + t]
                + partial[2 * BM + t] + partial[3 * BM + t];
        scores_part[((size_t)ns * BATCH + b) * STEP + s0 + t] = v;
    }
}

// K2: masked softmax; sums the 2 N-slice partials; atten aliases slice-0
// buffer (each thread reads its s-values before writing them).
__global__ __launch_bounds__(256) void softmax_kernel(
    const float* __restrict__ p0, const float* __restrict__ p1,
    const int* __restrict__ lens_raw, float* __restrict__ atten)
{
    __shared__ float wmax[4], wsum[4];
    int b = blockIdx.x;
    long long len = load_len(lens_raw, b);
    int t = threadIdx.x;
    const float* r0 = p0 + (size_t)b * STEP;
    const float* r1 = p1 + (size_t)b * STEP;
    float* arow = atten + (size_t)b * STEP;

    float sv[STEP / 256];
    float locmax = -INFINITY;
#pragma unroll
    for (int k = 0; k < 8; ++k) {
        int s = t + k * 256;
        float v = ((long long)s < len) ? (r0[s] + r1[s]) : -INFINITY;
        sv[k] = v;
        locmax = fmaxf(locmax, v);
    }
    for (int o = 1; o < 64; o <<= 1) locmax = fmaxf(locmax, __shfl_xor(locmax, o));
    int wave = t >> 6, lane = t & 63;
    if (lane == 0) wmax[wave] = locmax;
    __syncthreads();
    float gmax = fmaxf(fmaxf(wmax[0], wmax[1]), fmaxf(wmax[2], wmax[3]));

    float ev[8];
    float locsum = 0.f;
#pragma unroll
    for (int k = 0; k < 8; ++k) {
        float e = (sv[k] == -INFINITY) ? 0.f : expf(sv[k] - gmax);
        ev[k] = e;
        locsum += e;
    }
    for (int o = 1; o < 64; o <<= 1) locsum += __shfl_xor(locsum, o);
    if (lane == 0) wsum[wave] = locsum;
    __syncthreads();
    float inv = 1.f / (wsum[0] + wsum[1] + wsum[2] + wsum[3]);
#pragma unroll
    for (int k = 0; k < 8; ++k) {
        int s = t + k * 256;
        arow[s] = ev[k] * inv;
    }
}

// K3a: partial[b,ch,h] = sum_{s in chunk, s<len} atten[b,s] * X[b,s,h]
__global__ __launch_bounds__(256) void wsum_kernel(
    const float* __restrict__ X, const int* __restrict__ lens_raw,
    const float* __restrict__ atten, float* __restrict__ partial)
{
    int ch = blockIdx.x;
    int b  = blockIdx.y;
    long long len = load_len(lens_raw, b);
    int t = threadIdx.x;
    int s0 = ch * CHS;
    long long send_ll = (long long)(s0 + CHS);
    if (send_ll > len) send_ll = len;
    int send = (int)send_ll;

    const float* arow = atten + (size_t)b * STEP;
    float2 acc = {0.f, 0.f};
    for (int s = s0; s < send; ++s) {
        float a = arow[s];
        float2 xv = *(const float2*)(X + ((size_t)b * STEP + s) * HIDDEN + 2 * t);
        acc.x = fmaf(a, xv.x, acc.x);
        acc.y = fmaf(a, xv.y, acc.y);
    }
    float* prow = partial + ((size_t)b * NCH + ch) * HIDDEN;
    *(float2*)(prow + 2 * t) = acc;      // skipped chunks write zeros
}

// K3b: out[b,h] = sum_ch partial[b,ch,h]
__global__ __launch_bounds__(256) void finalize_kernel(
    const float* __restrict__ partial, float* __restrict__ out)
{
    int b = blockIdx.x;
    int t = threadIdx.x;
    float2 a = {0.f, 0.f};
#pragma unroll
    for (int ch = 0; ch < NCH; ++ch) {
        const float* prow = partial + ((size_t)b * NCH + ch) * HIDDEN;
        float2 v = *(const float2*)(prow + 2 * t);
        a.x += v.x;
        a.y += v.y;
    }
    *(float2*)(out + (size_t)b * HIDDEN + 2 * t) = a;
}

extern "C" void kernel_launch(void* const* d_in, const int* in_sizes, int n_in,
                              void* d_out, int out_size, void* d_ws, size_t ws_size,
                              hipStream_t stream) {
    const float* X    = (const float*)d_in[0];
    const int*   lens = (const int*)d_in[1];   // dtype sniffed on device
    const float* W    = (const float*)d_in[2];
    const float* bias = (const float*)d_in[3];
    const float* ctx  = (const float*)d_in[4];
    float* out = (float*)d_out;

    char* ws = (char*)d_ws;
    float* sp      = (float*)ws;                    // [2][B*S] = 512 KB
    float* atten   = sp;                            // aliases slice-0 (safe)
    float* partial = (float*)(ws + 512 * 1024);     // 1 MB
    short* wglds   = (short*)(ws + 1536 * 1024);    // 1 MB pre-swizzled W

    // allow 128 KB dynamic LDS (deterministic, no stream work)
    (void)hipFuncSetAttribute((const void*)scores_mfma_kernel,
                              hipFuncAttributeMaxDynamicSharedMemorySize,
                              128 * 1024);

    wsplit_kernel<<<dim3(ATTEN), 512, 0, stream>>>(W, wglds);
    scores_mfma_kernel<<<dim3(NS, BATCH * (STEP / BM)), THREADS, 128 * 1024, stream>>>(
        X, lens, wglds, bias, ctx, sp);
    softmax_kernel<<<dim3(BATCH), 256, 0, stream>>>(
        sp, sp + (size_t)BATCH * STEP, lens, atten);
    wsum_kernel<<<dim3(NCH, BATCH), 256, 0, stream>>>(X, lens, atten, partial);
    finalize_kernel<<<dim3(BATCH), 256, 0, stream>>>(partial, out);
}